// Round 3
// baseline (1490.382 us; speedup 1.0000x reference)
//
#include <hip/hip_runtime.h>
#include <hip/hip_bf16.h>

// Causal self-attention, fp32. B=2, L=S=2048, H=16, E=D=64.
// scores = Q·K^T (per b,h), mask j>i, softmax(scale*scores), out = A·V.
//
// Block = 256 thr = 4 waves, owns QB=64 q-rows of one (b,h).
// Lane decomposition: tg = lane>>4 splits each 64-row KV tile 4-way (16 rows each);
// within a tg-group, p = lane&15 -> pair pr = p>>1 owns q-rows (r0, r0+1), and
// eh = p&1 splits E (for QK^T partial dots, merged via __shfl_xor(.,1)) and
// D (for PV accumulation). 2 rows/lane halves LDS reads per FLOP vs 1 row/lane:
// 4 FLOP per LDS fp32 (VALU/LDS balanced) instead of 2 (LDS-bound).
// LDS swizzle: physical col = c ^ tg(row) ^ ((c&8)>>1) -> the 8 unique broadcast
// addresses per ds_read_b128 cover all 8 bank quads (conflict-free).
// fp32 throughout (no fp32 MFMA on CDNA4 -> VALU roofline ~157 TF).

#define B_ 2
#define L_ 2048
#define H_ 16
#define E_ 64
#define QB 64
#define KB 64

__device__ __forceinline__ void fma4(float4& a, float s, const float4 v) {
    a.x = __builtin_fmaf(s, v.x, a.x);
    a.y = __builtin_fmaf(s, v.y, a.y);
    a.z = __builtin_fmaf(s, v.z, a.z);
    a.w = __builtin_fmaf(s, v.w, a.w);
}

__global__ __launch_bounds__(256, 2)
void attn_fwd_f32(const float* __restrict__ Q, const float* __restrict__ K,
                  const float* __restrict__ V, const float* __restrict__ scale_p,
                  float* __restrict__ O) {
    // [0..1023] K-tile (64 rows x 16 float4), [1024..2047] V-tile
    __shared__ float4 smem[2048];

    const int qt   = (int)gridDim.x - 1 - (int)blockIdx.x;  // heavy blocks first
    const int bh   = blockIdx.y;
    const int b    = bh >> 4;
    const int h    = bh & 15;
    const int tid  = threadIdx.x;
    const int lane = tid & 63;
    const int wv   = tid >> 6;
    const int tg   = lane >> 4;        // KV sub-range tg*16 .. tg*16+15
    const int p    = lane & 15;
    const int pr   = p >> 1;           // pair index 0..7
    const int eh   = p & 1;            // E/D half selector
    const int r0   = wv * 16 + pr * 2; // block-local rows r0, r0+1
    const int i0   = qt * QB + r0;     // global q rows (i0 even, i1 = i0+1 odd)
    const int i1   = i0 + 1;
    const float scale = *scale_p;

    // ---- my Q half-rows: q{0,1}[ee] = float4 col (eh*8+ee) of rows i0,i1 ----
    float4 q0[8], q1[8];
    {
        const float4* q0p = reinterpret_cast<const float4*>(
            Q + (((size_t)b * L_ + i0) * H_ + h) * E_) + eh * 8;
        const float4* q1p = reinterpret_cast<const float4*>(
            Q + (((size_t)b * L_ + i1) * H_ + h) * E_) + eh * 8;
#pragma unroll
        for (int ee = 0; ee < 8; ++ee) { q0[ee] = q0p[ee]; q1[ee] = q1p[ee]; }
    }

    float4 acc0[8], acc1[8];
#pragma unroll
    for (int ee = 0; ee < 8; ++ee) {
        acc0[ee] = make_float4(0.f, 0.f, 0.f, 0.f);
        acc1[ee] = make_float4(0.f, 0.f, 0.f, 0.f);
    }
    float m0 = -1e30f, m1 = -1e30f, l0 = 0.f, l1 = 0.f;

    const int ntiles = qt + 1;
    for (int t = 0; t < ntiles; ++t) {
        const int j0 = t * KB;

        // ---- stage K,V tile; swizzle cs = c ^ tg(row) ^ (bit3(c)->bit2) ----
#pragma unroll
        for (int kk = 0; kk < 4; ++kk) {
            const int fi = tid + kk * 256;                 // float4 idx 0..1023
            const int r  = fi >> 4;                        // tile row 0..63
            const int c  = fi & 15;                        // float4 col 0..15
            const int cs = c ^ ((r >> 4) & 3) ^ ((c >> 3) << 2);
            const size_t gro = (((size_t)b * L_ + (j0 + r)) * H_ + h) * E_;
            smem[r * 16 + cs]        = reinterpret_cast<const float4*>(K + gro)[c];
            smem[1024 + r * 16 + cs] = reinterpret_cast<const float4*>(V + gro)[c];
        }
        __syncthreads();

        const int jb = j0 + tg * 16;
        if (jb <= i1) {   // jb even, i1 odd => jb <= i0 too: both rows active
            int nv0 = i0 - jb + 1; if (nv0 > 16) nv0 = 16;   // >=1
            int nv1 = nv0 + 1;     if (nv1 > 16) nv1 = 16;

            // ---- scores: 16 K-rows, half-E dots, pair-merged ----
            float s0[16], s1[16];
#pragma unroll
            for (int u = 0; u < 16; ++u) {
                const float4* kr = &smem[(tg * 16 + u) * 16];
                float4 a0 = make_float4(0.f, 0.f, 0.f, 0.f);
                float4 a1 = make_float4(0.f, 0.f, 0.f, 0.f);
#pragma unroll
                for (int ee = 0; ee < 8; ++ee) {
                    const float4 kv = kr[(eh * 8 + ee) ^ tg ^ (eh << 2)];
                    a0.x = __builtin_fmaf(q0[ee].x, kv.x, a0.x);
                    a0.y = __builtin_fmaf(q0[ee].y, kv.y, a0.y);
                    a0.z = __builtin_fmaf(q0[ee].z, kv.z, a0.z);
                    a0.w = __builtin_fmaf(q0[ee].w, kv.w, a0.w);
                    a1.x = __builtin_fmaf(q1[ee].x, kv.x, a1.x);
                    a1.y = __builtin_fmaf(q1[ee].y, kv.y, a1.y);
                    a1.z = __builtin_fmaf(q1[ee].z, kv.z, a1.z);
                    a1.w = __builtin_fmaf(q1[ee].w, kv.w, a1.w);
                }
                const float h0 = (a0.x + a0.y) + (a0.z + a0.w);
                const float h1 = (a1.x + a1.y) + (a1.z + a1.w);
                s0[u] = h0 + __shfl_xor(h0, 1, 64);   // pair lanes diverge together
                s1[u] = h1 + __shfl_xor(h1, 1, 64);
            }

            // ---- mask + scale + tile max ----
            float mt0 = -1e30f, mt1 = -1e30f;
#pragma unroll
            for (int u = 0; u < 16; ++u) {
                s0[u] = (u < nv0) ? s0[u] * scale : -1e30f;
                s1[u] = (u < nv1) ? s1[u] * scale : -1e30f;
                mt0 = fmaxf(mt0, s0[u]);
                mt1 = fmaxf(mt1, s1[u]);
            }
            const float mn0 = fmaxf(m0, mt0);
            const float mn1 = fmaxf(m1, mt1);
            if (__any(mn0 > m0 || mn1 > m1)) {
                const float f0 = __expf(m0 - mn0);
                const float f1 = __expf(m1 - mn1);
                l0 *= f0; l1 *= f1;
#pragma unroll
                for (int ee = 0; ee < 8; ++ee) {
                    acc0[ee].x *= f0; acc0[ee].y *= f0; acc0[ee].z *= f0; acc0[ee].w *= f0;
                    acc1[ee].x *= f1; acc1[ee].y *= f1; acc1[ee].z *= f1; acc1[ee].w *= f1;
                }
            }
            m0 = mn0; m1 = mn1;

            // ---- exp + PV (masked u give pu == 0) ----
#pragma unroll
            for (int u = 0; u < 16; ++u) {
                const float pu0 = __expf(s0[u] - m0);
                const float pu1 = __expf(s1[u] - m1);
                l0 += pu0; l1 += pu1;
                const float4* vr = &smem[1024 + (tg * 16 + u) * 16];
#pragma unroll
                for (int ee = 0; ee < 8; ++ee) {
                    const float4 vv = vr[(eh * 8 + ee) ^ tg ^ (eh << 2)];
                    fma4(acc0[ee], pu0, vv);
                    fma4(acc1[ee], pu1, vv);
                }
            }
        }
        __syncthreads();  // compute done before next tile overwrites LDS
    }

    // ---- merge 4 tg-partials per row: scalars via butterfly (xor 16, 32) ----
    float b0 = fmaxf(m0, __shfl_xor(m0, 16, 64));
    const float M0 = fmaxf(b0, __shfl_xor(b0, 32, 64));
    float b1 = fmaxf(m1, __shfl_xor(m1, 16, 64));
    const float M1 = fmaxf(b1, __shfl_xor(b1, 32, 64));
    const float f0 = __expf(m0 - M0);      // 0 for never-active partials
    const float f1 = __expf(m1 - M1);
    float lf0 = l0 * f0;
    lf0 += __shfl_xor(lf0, 16, 64); lf0 += __shfl_xor(lf0, 32, 64);
    float lf1 = l1 * f1;
    lf1 += __shfl_xor(lf1, 16, 64); lf1 += __shfl_xor(lf1, 32, 64);
    const float s0f = f0 / lf0;
    const float s1f = f1 / lf1;
#pragma unroll
    for (int ee = 0; ee < 8; ++ee) {
        acc0[ee].x *= s0f; acc0[ee].y *= s0f; acc0[ee].z *= s0f; acc0[ee].w *= s0f;
        acc1[ee].x *= s1f; acc1[ee].y *= s1f; acc1[ee].z *= s1f; acc1[ee].w *= s1f;
    }

    // ---- acc merge across tgs via LDS (slot XOR ee^pr spreads bank quads) ----
    // layout: idx = tgp*1024 + row_local*16 + eh*8 + (ee^pr)
    if (tg >= 2) {
        const int base = (tg - 2) * 1024 + r0 * 16 + eh * 8;
#pragma unroll
        for (int ee = 0; ee < 8; ++ee) {
            smem[base + (ee ^ pr)]      = acc0[ee];
            smem[base + 16 + (ee ^ pr)] = acc1[ee];
        }
    }
    __syncthreads();
    if (tg < 2) {   // tg0 += tg2, tg1 += tg3
        const int base = tg * 1024 + r0 * 16 + eh * 8;
#pragma unroll
        for (int ee = 0; ee < 8; ++ee) {
            const float4 v0 = smem[base + (ee ^ pr)];
            const float4 v1 = smem[base + 16 + (ee ^ pr)];
            acc0[ee].x += v0.x; acc0[ee].y += v0.y; acc0[ee].z += v0.z; acc0[ee].w += v0.w;
            acc1[ee].x += v1.x; acc1[ee].y += v1.y; acc1[ee].z += v1.z; acc1[ee].w += v1.w;
        }
    }
    __syncthreads();
    if (tg == 1) {
        const int base = r0 * 16 + eh * 8;
#pragma unroll
        for (int ee = 0; ee < 8; ++ee) {
            smem[base + (ee ^ pr)]      = acc0[ee];
            smem[base + 16 + (ee ^ pr)] = acc1[ee];
        }
    }
    __syncthreads();
    if (tg == 0) {
        const int base = r0 * 16 + eh * 8;
        float4* o0 = reinterpret_cast<float4*>(
            O + (((size_t)b * L_ + i0) * H_ + h) * E_) + eh * 8;
        float4* o1 = reinterpret_cast<float4*>(
            O + (((size_t)b * L_ + i1) * H_ + h) * E_) + eh * 8;
#pragma unroll
        for (int ee = 0; ee < 8; ++ee) {
            const float4 v0 = smem[base + (ee ^ pr)];
            const float4 v1 = smem[base + 16 + (ee ^ pr)];
            o0[ee] = make_float4(acc0[ee].x + v0.x, acc0[ee].y + v0.y,
                                 acc0[ee].z + v0.z, acc0[ee].w + v0.w);
            o1[ee] = make_float4(acc1[ee].x + v1.x, acc1[ee].y + v1.y,
                                 acc1[ee].z + v1.z, acc1[ee].w + v1.w);
        }
    }
}

extern "C" void kernel_launch(void* const* d_in, const int* in_sizes, int n_in,
                              void* d_out, int out_size, void* d_ws, size_t ws_size,
                              hipStream_t stream) {
    const float* Q = (const float*)d_in[0];
    const float* K = (const float*)d_in[1];
    const float* V = (const float*)d_in[2];
    const float* scale = (const float*)d_in[3];
    float* O = (float*)d_out;

    dim3 grid(L_ / QB, B_ * H_);  // (32 q-tiles, 32 b*h)
    attn_fwd_f32<<<grid, 256, 0, stream>>>(Q, K, V, scale, O);
}

// Round 4
// 929.405 us; speedup vs baseline: 1.6036x; 1.6036x over previous
//
#include <hip/hip_runtime.h>
#include <hip/hip_bf16.h>

// Causal self-attention, fp32. B=2, L=S=2048, H=16, E=D=64.
// scores = Q·K^T (per b,h), mask j>i, softmax(scale*scores), out = A·V.
//
// Block = 512 thr = 8 waves, owns QB=64 q-rows of one (b,h); 8 lanes per row:
//   row_local = wv*8 + (lane&7); eh = (lane>>3)&1 splits E (QK^T partial dots,
//   merged via __shfl_xor(.,8)) and D (PV accumulation halves);
//   tg = lane>>4 splits each 64-row KV tile 4-way (16 rows each; merged at end).
// Per-lane regs: q 32 + acc 32 + s 16 = 80 core -> NO SPILLS (round-3 kernel
// spilled at 128 VGPRs -> 2.6 GB scratch traffic, 1470us).
// LDS swizzle: physical col = c ^ tg(row) ^ ((c>>3)<<2): the 8 distinct broadcast
// addresses per ds_read_b128 (4 tg-rows x 2 eh col-halves) cover all 8 bank quads.
// fp32 throughout (no fp32 MFMA on CDNA4 -> VALU roofline ~157 TF).

#define B_ 2
#define L_ 2048
#define H_ 16
#define E_ 64
#define QB 64
#define KB 64

__device__ __forceinline__ void fma4(float4& a, float s, const float4 v) {
    a.x = __builtin_fmaf(s, v.x, a.x);
    a.y = __builtin_fmaf(s, v.y, a.y);
    a.z = __builtin_fmaf(s, v.z, a.z);
    a.w = __builtin_fmaf(s, v.w, a.w);
}

__global__ __launch_bounds__(512, 2)
void attn_fwd_f32(const float* __restrict__ Q, const float* __restrict__ K,
                  const float* __restrict__ V, const float* __restrict__ scale_p,
                  float* __restrict__ O) {
    // [0..1023] K-tile (64 rows x 16 float4), [1024..2047] V-tile
    __shared__ float4 smem[2048];

    const int qt   = (int)gridDim.x - 1 - (int)blockIdx.x;  // heavy blocks first
    const int bh   = blockIdx.y;
    const int b    = bh >> 4;
    const int h    = bh & 15;
    const int tid  = threadIdx.x;
    const int lane = tid & 63;
    const int wv   = tid >> 6;              // wave 0..7
    const int row_local = wv * 8 + (lane & 7);
    const int eh   = (lane >> 3) & 1;       // E/D half selector
    const int tg   = lane >> 4;             // KV sub-range tg*16 .. tg*16+15
    const int i    = qt * QB + row_local;   // global q row
    const float scale = *scale_p;

    // ---- my Q half-row: q[ee] = float4 col (eh*8+ee) of row i  (32 regs) ----
    float4 q[8];
    {
        const float4* qp = reinterpret_cast<const float4*>(
            Q + (((size_t)b * L_ + i) * H_ + h) * E_) + eh * 8;
#pragma unroll
        for (int ee = 0; ee < 8; ++ee) q[ee] = qp[ee];
    }

    float4 acc[8];                          // my D-half accumulator (32 regs)
#pragma unroll
    for (int ee = 0; ee < 8; ++ee) acc[ee] = make_float4(0.f, 0.f, 0.f, 0.f);
    float m = -1e30f, l = 0.f;

    const int ntiles = qt + 1;
    for (int t = 0; t < ntiles; ++t) {
        const int j0 = t * KB;

        // ---- stage K,V tile; swizzle cs = c ^ tg(row) ^ (bit3(c)->bit2) ----
#pragma unroll
        for (int kk = 0; kk < 2; ++kk) {
            const int fi = tid + kk * 512;                 // float4 idx 0..1023
            const int r  = fi >> 4;                        // tile row 0..63
            const int c  = fi & 15;                        // float4 col 0..15
            const int cs = c ^ ((r >> 4) & 3) ^ ((c >> 3) << 2);
            const size_t gro = (((size_t)b * L_ + (j0 + r)) * H_ + h) * E_;
            smem[r * 16 + cs]        = reinterpret_cast<const float4*>(K + gro)[c];
            smem[1024 + r * 16 + cs] = reinterpret_cast<const float4*>(V + gro)[c];
        }
        __syncthreads();

        const int jb = j0 + tg * 16;
        if (jb <= i) {
            int nv = i - jb + 1; if (nv > 16) nv = 16;     // valid count >= 1

            // ---- scores: 16 K-rows, half-E dots, eh-pair merged ----
            float s[16];
#pragma unroll
            for (int u = 0; u < 16; ++u) {
                const float4* kr = &smem[(tg * 16 + u) * 16];
                float4 a0 = make_float4(0.f, 0.f, 0.f, 0.f);
                float4 a1 = make_float4(0.f, 0.f, 0.f, 0.f);
#pragma unroll
                for (int ee = 0; ee < 8; ee += 2) {
                    const float4 k0 = kr[(eh * 8 + ee) ^ tg ^ (eh << 2)];
                    const float4 k1 = kr[(eh * 8 + ee + 1) ^ tg ^ (eh << 2)];
                    a0.x = __builtin_fmaf(q[ee].x, k0.x, a0.x);
                    a0.y = __builtin_fmaf(q[ee].y, k0.y, a0.y);
                    a0.z = __builtin_fmaf(q[ee].z, k0.z, a0.z);
                    a0.w = __builtin_fmaf(q[ee].w, k0.w, a0.w);
                    a1.x = __builtin_fmaf(q[ee + 1].x, k1.x, a1.x);
                    a1.y = __builtin_fmaf(q[ee + 1].y, k1.y, a1.y);
                    a1.z = __builtin_fmaf(q[ee + 1].z, k1.z, a1.z);
                    a1.w = __builtin_fmaf(q[ee + 1].w, k1.w, a1.w);
                }
                const float half = (a0.x + a1.x) + (a0.y + a1.y)
                                 + (a0.z + a1.z) + (a0.w + a1.w);
                s[u] = half + __shfl_xor(half, 8, 64);  // eh pair, no divergence
            }

            // ---- mask + scale + tile max ----
            float mt = -1e30f;
#pragma unroll
            for (int u = 0; u < 16; ++u) {
                s[u] = (u < nv) ? s[u] * scale : -1e30f;
                mt = fmaxf(mt, s[u]);
            }
            const float mn = fmaxf(m, mt);
            if (__any(mn > m)) {
                const float fr = __expf(m - mn);
                l *= fr;
#pragma unroll
                for (int ee = 0; ee < 8; ++ee) {
                    acc[ee].x *= fr; acc[ee].y *= fr;
                    acc[ee].z *= fr; acc[ee].w *= fr;
                }
            }
            m = mn;

            // ---- exp + PV (masked u give pu == 0) ----
#pragma unroll
            for (int u = 0; u < 16; ++u) {
                const float pu = __expf(s[u] - m);
                l += pu;
                const float4* vr = &smem[1024 + (tg * 16 + u) * 16];
#pragma unroll
                for (int ee = 0; ee < 8; ++ee) {
                    const float4 vv = vr[(eh * 8 + ee) ^ tg ^ (eh << 2)];
                    fma4(acc[ee], pu, vv);
                }
            }
        }
        __syncthreads();  // compute done before next tile overwrites LDS
    }

    // ---- merge 4 tg-partials per row (m,l identical across eh pair) ----
    float b0 = fmaxf(m, __shfl_xor(m, 16, 64));
    const float M = fmaxf(b0, __shfl_xor(b0, 32, 64));
    const float f = __expf(m - M);          // 0 for never-active partials
    float lf = l * f;
    lf += __shfl_xor(lf, 16, 64);
    lf += __shfl_xor(lf, 32, 64);
    const float sf = f / lf;
#pragma unroll
    for (int ee = 0; ee < 8; ++ee) {
        acc[ee].x *= sf; acc[ee].y *= sf; acc[ee].z *= sf; acc[ee].w *= sf;
    }

    // ---- acc merge across tgs via LDS: plane p = row_local*16 + eh*8 + ee ----
    if (tg >= 2) {
        const int base = (tg - 2) * 1024 + row_local * 16 + eh * 8;
#pragma unroll
        for (int ee = 0; ee < 8; ++ee) smem[base + ee] = acc[ee];
    }
    __syncthreads();
    if (tg < 2) {   // tg0 += tg2, tg1 += tg3
        const int base = tg * 1024 + row_local * 16 + eh * 8;
#pragma unroll
        for (int ee = 0; ee < 8; ++ee) {
            const float4 v = smem[base + ee];
            acc[ee].x += v.x; acc[ee].y += v.y;
            acc[ee].z += v.z; acc[ee].w += v.w;
        }
    }
    __syncthreads();
    if (tg == 1) {
        const int base = row_local * 16 + eh * 8;
#pragma unroll
        for (int ee = 0; ee < 8; ++ee) smem[base + ee] = acc[ee];
    }
    __syncthreads();
    if (tg == 0) {
        const int base = row_local * 16 + eh * 8;
        float4* op = reinterpret_cast<float4*>(
            O + (((size_t)b * L_ + i) * H_ + h) * E_) + eh * 8;
#pragma unroll
        for (int ee = 0; ee < 8; ++ee) {
            const float4 v = smem[base + ee];
            op[ee] = make_float4(acc[ee].x + v.x, acc[ee].y + v.y,
                                 acc[ee].z + v.z, acc[ee].w + v.w);
        }
    }
}

extern "C" void kernel_launch(void* const* d_in, const int* in_sizes, int n_in,
                              void* d_out, int out_size, void* d_ws, size_t ws_size,
                              hipStream_t stream) {
    const float* Q = (const float*)d_in[0];
    const float* K = (const float*)d_in[1];
    const float* V = (const float*)d_in[2];
    const float* scale = (const float*)d_in[3];
    float* O = (float*)d_out;

    dim3 grid(L_ / QB, B_ * H_);  // (32 q-tiles, 32 b*h)
    attn_fwd_f32<<<grid, 512, 0, stream>>>(Q, K, V, scale, O);
}

// Round 6
// 225.933 us; speedup vs baseline: 6.5966x; 4.1136x over previous
//
#include <hip/hip_runtime.h>
#include <hip/hip_bf16.h>

// Causal self-attention via MFMA, B=2 L=2048 H=16 E=D=64, fp32 I/O.
// Swapped QK^T: S^T = K·Q^T with mfma_f32_32x32x16_bf16 (A=K rows, B=Q cols).
//   C-frag: col = q = lane&31, row = kv = (reg&3) + 8*(reg>>2) + 4*(lane>>5).
// Precision: QK^T bf16 hi/lo 3-term (≈fp32); P single bf16; PV V hi/lo 2-term.
// PV: O^T = V^T·P^T (A = V^T staged transposed in LDS, B = P^T built in-register
//   from the S C-frag via 2 shuffles per K-slice — no LDS round-trip).
// Block = 256 thr = 4 waves × 32 q-rows (QBLK=128). Grid = 256 persistent
// blocks; block (j,bh) does chunks qt=j and qt=15-j -> 36 KV-tiles each (balanced).
// LDS 32KB: K_hi, K_lo, VT_hi, VT_lo, each [64 rows][128B] with XOR swizzle
//   (dword w' = w ^ (g(row)<<2)): K reads conflict-free (8 addrs/bank-quad for
//   b128 = optimal), VT reads 2-way.
// R5 audit fix: P-exchange now SENDS W[(sa+1-hb)*2+h] (partner's s-slot) and
// keeps W[(sa+hb)*2+h]; previous version shuffled the kept value -> partner
// received wrong s-slot (kv off by 8).

#define B_ 2
#define L_ 2048
#define H_ 16
#define E_ 64

typedef short s8x  __attribute__((ext_vector_type(8)));   // 8 bf16 (4 VGPR)
typedef float f16x __attribute__((ext_vector_type(16)));  // MFMA C/D

__device__ __forceinline__ unsigned short f2bf(float f) {
    __hip_bfloat16 h = __float2bfloat16(f);   // RN
    return __builtin_bit_cast(unsigned short, h);
}
__device__ __forceinline__ float bf2f(unsigned short u) {
    __hip_bfloat16 h = __builtin_bit_cast(__hip_bfloat16, u);
    return __bfloat162float(h);
}
__device__ __forceinline__ unsigned int pk(unsigned short lo, unsigned short hi) {
    return (unsigned int)lo | ((unsigned int)hi << 16);
}

__global__ __launch_bounds__(256, 1)
void attn_mfma(const float* __restrict__ Q, const float* __restrict__ K,
               const float* __restrict__ V, const float* __restrict__ scale_p,
               float* __restrict__ O) {
    // dwords: K_hi [0,2048) K_lo [2048,4096) VT_hi [4096,6144) VT_lo [6144,8192)
    __shared__ unsigned int lds[8192];

    const int tid  = threadIdx.x;
    const int lane = tid & 63;
    const int wv   = tid >> 6;        // wave 0..3
    const int c    = lane & 31;       // MFMA col / row-in-frag
    const int hb   = lane >> 5;       // half-wave (k-group / crow bit)
    const int bh   = blockIdx.x & 31; // same-bh blocks share XCD (id%8) -> K/V L2 reuse
    const int jj   = blockIdx.x >> 5; // 0..7
    const int b    = bh >> 4;
    const int h    = bh & 15;
    const float scale = *scale_p;

    const int gk = c & 7;                            // K-region read swizzle
    const int gv = (((c >> 2) & 3) << 1) | (c & 1);  // VT-region read swizzle
    const size_t bh_off = ((size_t)b * L_ * H_ + h) * E_;  // + q*1024 per row
    const char* ldsb = (const char*)lds;

    for (int ci = 0; ci < 2; ++ci) {
        const int qt  = ci ? (15 - jj) : jj;   // chunk pair (j, 15-j): 36 tiles total
        const int q0w = qt * 128 + wv * 32;    // wave's q base
        const int qg  = q0w + c;               // lane's q (its MFMA column)

        // ---- Q B-frags (scale folded in, then hi/lo split) ----
        const float* Qrow = Q + bh_off + (size_t)qg * 1024;
        s8x qh[4], ql[4];
#pragma unroll
        for (int ks = 0; ks < 4; ++ks) {
            const float* qp = Qrow + ks * 16 + hb * 8;
            float4 f0 = *(const float4*)(qp);
            float4 f1 = *(const float4*)(qp + 4);
            float qv[8] = {f0.x, f0.y, f0.z, f0.w, f1.x, f1.y, f1.z, f1.w};
            union { unsigned short u[8]; s8x v; } th, tl;
#pragma unroll
            for (int e = 0; e < 8; ++e) {
                const float fs = qv[e] * scale;
                const unsigned short hh = f2bf(fs);
                th.u[e] = hh;
                tl.u[e] = f2bf(fs - bf2f(hh));
            }
            qh[ks] = th.v; ql[ks] = tl.v;
        }

        f16x sA, sB, oA, oB;
#pragma unroll
        for (int i2 = 0; i2 < 16; ++i2) { oA[i2] = 0.f; oB[i2] = 0.f; }
        float m = -1e30f, l = 0.f;

        const int nt = 2 * qt + 2;
        for (int t = 0; t < nt; ++t) {
            const int j0 = t * 64;
            // ================= stage K,V tile (hi/lo bf16, swizzled) =================
            {
                const float* Kt = K + bh_off + (size_t)j0 * 1024;
                const float* Vt = V + bh_off + (size_t)j0 * 1024;
#pragma unroll
                for (int kk = 0; kk < 4; ++kk) {
                    const int kv = kk * 16 + (tid >> 4);
                    const int e4 = tid & 15;
                    const float4 v = *(const float4*)(Kt + (size_t)kv * 1024 + e4 * 4);
                    const unsigned short hx = f2bf(v.x), hy = f2bf(v.y),
                                         hz = f2bf(v.z), hw = f2bf(v.w);
                    const unsigned short lx = f2bf(v.x - bf2f(hx)), ly = f2bf(v.y - bf2f(hy)),
                                         lz = f2bf(v.z - bf2f(hz)), lw = f2bf(v.w - bf2f(hw));
                    const int w = (e4 * 2) ^ ((kv & 7) << 2);
                    *(uint2*)&lds[kv * 32 + w]        = make_uint2(pk(hx, hy), pk(hz, hw));
                    *(uint2*)&lds[2048 + kv * 32 + w] = make_uint2(pk(lx, ly), pk(lz, lw));
                }
                const int d4 = (tid & 15) * 4;
                const int kb = tid >> 4;   // kv4 = kb*4
                const float4 f0 = *(const float4*)(Vt + (size_t)(kb * 4 + 0) * 1024 + d4);
                const float4 f1 = *(const float4*)(Vt + (size_t)(kb * 4 + 1) * 1024 + d4);
                const float4 f2 = *(const float4*)(Vt + (size_t)(kb * 4 + 2) * 1024 + d4);
                const float4 f3 = *(const float4*)(Vt + (size_t)(kb * 4 + 3) * 1024 + d4);
#pragma unroll
                for (int qq = 0; qq < 4; ++qq) {   // in-register 4x4 transpose
                    const float e0 = ((const float*)&f0)[qq], e1 = ((const float*)&f1)[qq],
                                e2 = ((const float*)&f2)[qq], e3 = ((const float*)&f3)[qq];
                    const unsigned short h0 = f2bf(e0), h1 = f2bf(e1),
                                         h2 = f2bf(e2), h3 = f2bf(e3);
                    const unsigned short l0 = f2bf(e0 - bf2f(h0)), l1 = f2bf(e1 - bf2f(h1)),
                                         l2 = f2bf(e2 - bf2f(h2)), l3 = f2bf(e3 - bf2f(h3));
                    const int d = d4 + qq;
                    const int g = (((d >> 2) & 3) << 1) | (d & 1);
                    const int w = (kb * 2) ^ (g << 2);
                    *(uint2*)&lds[4096 + d * 32 + w] = make_uint2(pk(h0, h1), pk(h2, h3));
                    *(uint2*)&lds[6144 + d * 32 + w] = make_uint2(pk(l0, l1), pk(l2, l3));
                }
            }
            __syncthreads();

            if (j0 <= q0w + 31) {   // wave-uniform: skip fully-masked tiles
                // ================= QK^T (hi*hi + hi*lo + lo*hi) =================
#pragma unroll
                for (int i2 = 0; i2 < 16; ++i2) { sA[i2] = 0.f; sB[i2] = 0.f; }
#pragma unroll
                for (int ks = 0; ks < 4; ++ks) {
                    const int wq = ((ks * 8 + hb * 4) ^ (gk << 2)) * 4;
                    const s8x kAh = *(const s8x*)(ldsb + c * 128 + wq);
                    const s8x kAl = *(const s8x*)(ldsb + 8192 + c * 128 + wq);
                    const s8x kBh = *(const s8x*)(ldsb + (32 + c) * 128 + wq);
                    const s8x kBl = *(const s8x*)(ldsb + 8192 + (32 + c) * 128 + wq);
                    sA = __builtin_amdgcn_mfma_f32_32x32x16_bf16(kAh, qh[ks], sA, 0, 0, 0);
                    sA = __builtin_amdgcn_mfma_f32_32x32x16_bf16(kAh, ql[ks], sA, 0, 0, 0);
                    sA = __builtin_amdgcn_mfma_f32_32x32x16_bf16(kAl, qh[ks], sA, 0, 0, 0);
                    sB = __builtin_amdgcn_mfma_f32_32x32x16_bf16(kBh, qh[ks], sB, 0, 0, 0);
                    sB = __builtin_amdgcn_mfma_f32_32x32x16_bf16(kBh, ql[ks], sB, 0, 0, 0);
                    sB = __builtin_amdgcn_mfma_f32_32x32x16_bf16(kBl, qh[ks], sB, 0, 0, 0);
                }
                // ---- causal mask (only near-diagonal tiles branch in) ----
                if (j0 + 63 > q0w) {
#pragma unroll
                    for (int i2 = 0; i2 < 16; ++i2) {
                        const int kvl = (i2 & 3) + 8 * (i2 >> 2) + 4 * hb;
                        sA[i2] = (j0 + kvl > qg)      ? -1e30f : sA[i2];
                        sB[i2] = (j0 + 32 + kvl > qg) ? -1e30f : sB[i2];
                    }
                }
                // ---- online softmax (row = q = lane-local col; partner lane^32) ----
                float mt = -1e30f;
#pragma unroll
                for (int i2 = 0; i2 < 16; ++i2) { mt = fmaxf(mt, sA[i2]); mt = fmaxf(mt, sB[i2]); }
                mt = fmaxf(mt, __shfl_xor(mt, 32, 64));
                const float mn = fmaxf(m, mt);
                const float fr = __expf(m - mn);   // 0 on first real tile, 1 if unchanged
                m = mn;
                l *= fr;
#pragma unroll
                for (int i2 = 0; i2 < 16; ++i2) { oA[i2] *= fr; oB[i2] *= fr; }
                float lt = 0.f;
#pragma unroll
                for (int i2 = 0; i2 < 16; ++i2) {
                    const float pA = __expf(sA[i2] - m);
                    const float pB = __expf(sB[i2] - m);
                    sA[i2] = pA; sB[i2] = pB;      // reuse S regs as P
                    lt += pA + pB;
                }
                lt += __shfl_xor(lt, 32, 64);
                l += lt;
                // ---- pack P -> bf16 words W[Mt*8 + s*2 + h] = kv {32Mt+8s+4hb+2h, +1} ----
                unsigned int W[16];
#pragma unroll
                for (int ss = 0; ss < 4; ++ss)
#pragma unroll
                for (int hh2 = 0; hh2 < 2; ++hh2) {
                    const int r0 = 4 * ss + 2 * hh2;
                    W[ss * 2 + hh2]     = pk(f2bf(sA[r0]), f2bf(sA[r0 + 1]));
                    W[8 + ss * 2 + hh2] = pk(f2bf(sB[r0]), f2bf(sB[r0 + 1]));
                }
                // ================= PV: O^T += V^T · P^T (V hi/lo) =================
                // Lane needs kv run [ks*16 + hb*8, +8) => s-slot s' = 2*(ks&1)+hb,
                // pairs from owner-hb {0,0,1,1} x h {0,1}. Keep my W[s'], SEND my
                // W[partner s' = sa+1-hb] (that's what lane^32 needs from me).
#pragma unroll
                for (int ks = 0; ks < 4; ++ks) {
                    const int Mt = ks >> 1;
                    const int sa = (ks & 1) * 2;
                    const unsigned int keep0 = hb ? W[Mt * 8 + (sa + 1) * 2 + 0]
                                                  : W[Mt * 8 + sa * 2 + 0];
                    const unsigned int keep1 = hb ? W[Mt * 8 + (sa + 1) * 2 + 1]
                                                  : W[Mt * 8 + sa * 2 + 1];
                    const unsigned int send0 = hb ? W[Mt * 8 + sa * 2 + 0]
                                                  : W[Mt * 8 + (sa + 1) * 2 + 0];
                    const unsigned int send1 = hb ? W[Mt * 8 + sa * 2 + 1]
                                                  : W[Mt * 8 + (sa + 1) * 2 + 1];
                    const unsigned int swp0 = (unsigned int)__shfl_xor((int)send0, 32, 64);
                    const unsigned int swp1 = (unsigned int)__shfl_xor((int)send1, 32, 64);
                    union { unsigned int u[4]; s8x v; } pf;
                    pf.u[0] = hb ? swp0 : keep0;   // kv ks*16+hb*8 + {0,1}
                    pf.u[1] = hb ? swp1 : keep1;   // + {2,3}
                    pf.u[2] = hb ? keep0 : swp0;   // + {4,5}
                    pf.u[3] = hb ? keep1 : swp1;   // + {6,7}
                    const int wvv = ((ks * 8 + hb * 4) ^ (gv << 2)) * 4;
                    const s8x vAh = *(const s8x*)(ldsb + 16384 + c * 128 + wvv);
                    const s8x vAl = *(const s8x*)(ldsb + 24576 + c * 128 + wvv);
                    const s8x vBh = *(const s8x*)(ldsb + 16384 + (32 + c) * 128 + wvv);
                    const s8x vBl = *(const s8x*)(ldsb + 24576 + (32 + c) * 128 + wvv);
                    oA = __builtin_amdgcn_mfma_f32_32x32x16_bf16(vAh, pf.v, oA, 0, 0, 0);
                    oA = __builtin_amdgcn_mfma_f32_32x32x16_bf16(vAl, pf.v, oA, 0, 0, 0);
                    oB = __builtin_amdgcn_mfma_f32_32x32x16_bf16(vBh, pf.v, oB, 0, 0, 0);
                    oB = __builtin_amdgcn_mfma_f32_32x32x16_bf16(vBl, pf.v, oB, 0, 0, 0);
                }
            }
            __syncthreads();   // protect LDS before next tile's staging
        }
        // ================= epilogue: O[q][d] = o/l =================
        const float inv = 1.0f / l;
        float* Orow = O + bh_off + (size_t)qg * 1024;
#pragma unroll
        for (int i2 = 0; i2 < 16; ++i2) {
            const int d = (i2 & 3) + 8 * (i2 >> 2) + 4 * hb;
            Orow[d]      = oA[i2] * inv;
            Orow[32 + d] = oB[i2] * inv;
        }
    }
}

extern "C" void kernel_launch(void* const* d_in, const int* in_sizes, int n_in,
                              void* d_out, int out_size, void* d_ws, size_t ws_size,
                              hipStream_t stream) {
    const float* Q = (const float*)d_in[0];
    const float* K = (const float*)d_in[1];
    const float* V = (const float*)d_in[2];
    const float* scale = (const float*)d_in[3];
    float* O = (float*)d_out;

    attn_mfma<<<dim3(256), 256, 0, stream>>>(Q, K, V, scale, O);
}

// Round 8
// 176.529 us; speedup vs baseline: 8.4427x; 1.2799x over previous
//
#include <hip/hip_runtime.h>
#include <hip/hip_bf16.h>
#include <stdint.h>

// Causal self-attention via MFMA, B=2 L=2048 H=16 E=D=64, fp32 I/O.
// Swapped QK^T: S^T = K·Q^T with mfma_f32_32x32x16_bf16 (A=K rows, B=Q cols).
//   C-frag: col = q = lane&31, row = kv = (reg&3) + 8*(reg>>2) + 4*(lane>>5).
// Precision: QK^T bf16 hi/lo 3-term (≈fp32); P single bf16; PV V hi/lo 2-term.
//
// R8 = R7 audited + CU load-balance fix:
//   pack_kv: per (bh, 64-row tile) writes the exact 32KB swizzled LDS image
//     (K_hi | K_lo | VT_hi | VT_lo, 8KB each) into d_ws. One-time conversion.
//   attn_mfma_ws: grid 512 = (16 qt x 32 bh), one 128-row q-chunk per block.
//     qt map pairs CU-co-resident blocks (id, id+256) as qt={15-k, k} -> every
//     CU gets exactly 36 tiles (was 52 worst-case in R7's map).
//     id&31 = bh -> id%8 = bh%8: same-bh blocks share an XCD; 4 bh x 1MB packed
//     KV = 4MB = one XCD L2. 2 blocks/CU (64KB LDS each).
//     Tile loop: STAGE(next tile -> other LDS buf, global_load_lds 16B) issued
//     BEFORE compute(current); one __syncthreads per tile drains vmcnt.
// Fallback (ws too small): R6 monolithic kernel (passed at 226us).

#define B_ 2
#define L_ 2048
#define H_ 16
#define E_ 64

typedef short s8x  __attribute__((ext_vector_type(8)));   // 8 bf16 (4 VGPR)
typedef float f16x __attribute__((ext_vector_type(16)));  // MFMA C/D

__device__ __forceinline__ unsigned short f2bf(float f) {
    __hip_bfloat16 h = __float2bfloat16(f);   // RN
    return __builtin_bit_cast(unsigned short, h);
}
__device__ __forceinline__ float bf2f(unsigned short u) {
    __hip_bfloat16 h = __builtin_bit_cast(__hip_bfloat16, u);
    return __bfloat162float(h);
}
__device__ __forceinline__ unsigned int pk(unsigned short lo, unsigned short hi) {
    return (unsigned int)lo | ((unsigned int)hi << 16);
}
__device__ __forceinline__ void gload_lds16(const unsigned int* g, unsigned int* l) {
    auto* gp = reinterpret_cast<const __attribute__((address_space(1))) unsigned int*>(
        reinterpret_cast<uintptr_t>(g));
    auto* lp = reinterpret_cast<__attribute__((address_space(3))) unsigned int*>(
        reinterpret_cast<uintptr_t>(l));
    __builtin_amdgcn_global_load_lds(gp, lp, 16, 0, 0);
}

// ===================== pack kernel: K/V -> swizzled tile images =====================
__global__ __launch_bounds__(256)
void pack_kv(const float* __restrict__ K, const float* __restrict__ V,
             unsigned int* __restrict__ WS) {
    const int id  = blockIdx.x;        // bh*32 + t
    const int bh  = id >> 5;
    const int t   = id & 31;
    const int b   = bh >> 4;
    const int h   = bh & 15;
    const int tid = threadIdx.x;
    const size_t bh_off = ((size_t)b * L_ * H_ + h) * E_;
    const int j0 = t * 64;
    unsigned int* img = WS + (size_t)id * 8192;   // 32KB image (dwords)
    const float* Kt = K + bh_off + (size_t)j0 * 1024;
    const float* Vt = V + bh_off + (size_t)j0 * 1024;

#pragma unroll
    for (int kk = 0; kk < 4; ++kk) {
        const int kv = kk * 16 + (tid >> 4);
        const int e4 = tid & 15;
        const float4 v = *(const float4*)(Kt + (size_t)kv * 1024 + e4 * 4);
        const unsigned short hx = f2bf(v.x), hy = f2bf(v.y),
                             hz = f2bf(v.z), hw = f2bf(v.w);
        const unsigned short lx = f2bf(v.x - bf2f(hx)), ly = f2bf(v.y - bf2f(hy)),
                             lz = f2bf(v.z - bf2f(hz)), lw = f2bf(v.w - bf2f(hw));
        const int w = (e4 * 2) ^ ((kv & 7) << 2);
        *(uint2*)&img[kv * 32 + w]        = make_uint2(pk(hx, hy), pk(hz, hw));
        *(uint2*)&img[2048 + kv * 32 + w] = make_uint2(pk(lx, ly), pk(lz, lw));
    }
    const int d4 = (tid & 15) * 4;
    const int kb = tid >> 4;
    const float4 f0 = *(const float4*)(Vt + (size_t)(kb * 4 + 0) * 1024 + d4);
    const float4 f1 = *(const float4*)(Vt + (size_t)(kb * 4 + 1) * 1024 + d4);
    const float4 f2 = *(const float4*)(Vt + (size_t)(kb * 4 + 2) * 1024 + d4);
    const float4 f3 = *(const float4*)(Vt + (size_t)(kb * 4 + 3) * 1024 + d4);
#pragma unroll
    for (int qq = 0; qq < 4; ++qq) {   // in-register 4x4 transpose
        const float e0 = ((const float*)&f0)[qq], e1 = ((const float*)&f1)[qq],
                    e2 = ((const float*)&f2)[qq], e3 = ((const float*)&f3)[qq];
        const unsigned short h0 = f2bf(e0), h1 = f2bf(e1),
                             h2 = f2bf(e2), h3 = f2bf(e3);
        const unsigned short l0 = f2bf(e0 - bf2f(h0)), l1 = f2bf(e1 - bf2f(h1)),
                             l2 = f2bf(e2 - bf2f(h2)), l3 = f2bf(e3 - bf2f(h3));
        const int d = d4 + qq;
        const int g = (((d >> 2) & 3) << 1) | (d & 1);
        const int w = (kb * 2) ^ (g << 2);
        *(uint2*)&img[4096 + d * 32 + w] = make_uint2(pk(h0, h1), pk(h2, h3));
        *(uint2*)&img[6144 + d * 32 + w] = make_uint2(pk(l0, l1), pk(l2, l3));
    }
}

// ===================== attention kernel (packed ws, dbuf LDS) =====================
__global__ __launch_bounds__(256, 2)
void attn_mfma_ws(const float* __restrict__ Q, const unsigned int* __restrict__ WS,
                  const float* __restrict__ scale_p, float* __restrict__ O) {
    __shared__ unsigned int lds[16384];   // 2 x 32KB tile buffers

    const int tid  = threadIdx.x;
    const int lane = tid & 63;
    const int wv   = tid >> 6;
    const int c    = lane & 31;
    const int hb   = lane >> 5;
    const int id   = blockIdx.x;
    const int bh   = id & 31;             // id%8 = bh%8 -> bh-sticky XCD
    // CU-pairing: blocks id and id+256 co-reside on a CU; give them qt j and 15-j
    // -> each CU's two blocks total exactly 36 tiles.
    const int qt   = (id < 256) ? (15 - (id >> 5)) : ((id >> 5) - 8);
    const int b    = bh >> 4;
    const int h    = bh & 15;
    const float scale = *scale_p;

    const int gk = c & 7;
    const int gv = (((c >> 2) & 3) << 1) | (c & 1);
    const size_t bh_off = ((size_t)b * L_ * H_ + h) * E_;
    const char* ldsb = (const char*)lds;
    const unsigned int* imgs = WS + (size_t)bh * 32 * 8192;

    const int q0w = qt * 128 + wv * 32;
    const int qg  = q0w + c;

    // ---- Q B-frags (scale folded in, then hi/lo split) ----
    const float* Qrow = Q + bh_off + (size_t)qg * 1024;
    s8x qh[4], ql[4];
#pragma unroll
    for (int ks = 0; ks < 4; ++ks) {
        const float* qp = Qrow + ks * 16 + hb * 8;
        float4 f0 = *(const float4*)(qp);
        float4 f1 = *(const float4*)(qp + 4);
        float qv[8] = {f0.x, f0.y, f0.z, f0.w, f1.x, f1.y, f1.z, f1.w};
        union { unsigned short u[8]; s8x v; } th, tl;
#pragma unroll
        for (int e = 0; e < 8; ++e) {
            const float fs = qv[e] * scale;
            const unsigned short hh = f2bf(fs);
            th.u[e] = hh;
            tl.u[e] = f2bf(fs - bf2f(hh));
        }
        qh[ks] = th.v; ql[ks] = tl.v;
    }

    f16x sA, sB, oA, oB;
#pragma unroll
    for (int i2 = 0; i2 < 16; ++i2) { oA[i2] = 0.f; oB[i2] = 0.f; }
    float m = -1e30f, l = 0.f;

    const int nt = 2 * qt + 2;

    // stage tile 0 -> buf 0 (8 x 16B direct-to-LDS per thread = 32KB/block)
#pragma unroll
    for (int qq = 0; qq < 8; ++qq) {
        const int off = wv * 2048 + qq * 256 + lane * 4;   // dwords
        gload_lds16(imgs + off, &lds[off]);
    }
    __syncthreads();   // drains vmcnt -> tile 0 resident

    for (int t = 0; t < nt; ++t) {
        // ---- issue next tile's loads into the other buffer (hidden under compute) ----
        if (t + 1 < nt) {
            const unsigned int* img = imgs + (size_t)(t + 1) * 8192;
            unsigned int* db = &lds[((t + 1) & 1) * 8192];
#pragma unroll
            for (int qq = 0; qq < 8; ++qq) {
                const int off = wv * 2048 + qq * 256 + lane * 4;
                gload_lds16(img + off, db + off);
            }
        }
        const int j0 = t * 64;
        const int bb = (t & 1) * 32768;   // current buffer byte base

        if (j0 <= q0w + 31) {   // wave-uniform skip of fully-masked tiles
            // ================= QK^T (hi*hi + hi*lo + lo*hi) =================
#pragma unroll
            for (int i2 = 0; i2 < 16; ++i2) { sA[i2] = 0.f; sB[i2] = 0.f; }
#pragma unroll
            for (int ks = 0; ks < 4; ++ks) {
                const int wq = ((ks * 8 + hb * 4) ^ (gk << 2)) * 4;
                const s8x kAh = *(const s8x*)(ldsb + bb + c * 128 + wq);
                const s8x kAl = *(const s8x*)(ldsb + bb + 8192 + c * 128 + wq);
                const s8x kBh = *(const s8x*)(ldsb + bb + (32 + c) * 128 + wq);
                const s8x kBl = *(const s8x*)(ldsb + bb + 8192 + (32 + c) * 128 + wq);
                sA = __builtin_amdgcn_mfma_f32_32x32x16_bf16(kAh, qh[ks], sA, 0, 0, 0);
                sA = __builtin_amdgcn_mfma_f32_32x32x16_bf16(kAh, ql[ks], sA, 0, 0, 0);
                sA = __builtin_amdgcn_mfma_f32_32x32x16_bf16(kAl, qh[ks], sA, 0, 0, 0);
                sB = __builtin_amdgcn_mfma_f32_32x32x16_bf16(kBh, qh[ks], sB, 0, 0, 0);
                sB = __builtin_amdgcn_mfma_f32_32x32x16_bf16(kBh, ql[ks], sB, 0, 0, 0);
                sB = __builtin_amdgcn_mfma_f32_32x32x16_bf16(kBl, qh[ks], sB, 0, 0, 0);
            }
            // ---- causal mask (only near-diagonal tiles branch in) ----
            if (j0 + 63 > q0w) {
#pragma unroll
                for (int i2 = 0; i2 < 16; ++i2) {
                    const int kvl = (i2 & 3) + 8 * (i2 >> 2) + 4 * hb;
                    sA[i2] = (j0 + kvl > qg)      ? -1e30f : sA[i2];
                    sB[i2] = (j0 + 32 + kvl > qg) ? -1e30f : sB[i2];
                }
            }
            // ---- online softmax (row = q = lane col; partner lane^32) ----
            float mt = -1e30f;
#pragma unroll
            for (int i2 = 0; i2 < 16; ++i2) { mt = fmaxf(mt, sA[i2]); mt = fmaxf(mt, sB[i2]); }
            mt = fmaxf(mt, __shfl_xor(mt, 32, 64));
            const float mn = fmaxf(m, mt);
            const float fr = __expf(m - mn);
            m = mn;
            l *= fr;
#pragma unroll
            for (int i2 = 0; i2 < 16; ++i2) { oA[i2] *= fr; oB[i2] *= fr; }
            float lt = 0.f;
#pragma unroll
            for (int i2 = 0; i2 < 16; ++i2) {
                const float pA = __expf(sA[i2] - m);
                const float pB = __expf(sB[i2] - m);
                sA[i2] = pA; sB[i2] = pB;
                lt += pA + pB;
            }
            lt += __shfl_xor(lt, 32, 64);
            l += lt;
            // ---- pack P -> bf16 words W[Mt*8 + s*2 + h] = kv {32Mt+8s+4hb+2h, +1} ----
            unsigned int W[16];
#pragma unroll
            for (int ss = 0; ss < 4; ++ss)
#pragma unroll
            for (int hh2 = 0; hh2 < 2; ++hh2) {
                const int r0 = 4 * ss + 2 * hh2;
                W[ss * 2 + hh2]     = pk(f2bf(sA[r0]), f2bf(sA[r0 + 1]));
                W[8 + ss * 2 + hh2] = pk(f2bf(sB[r0]), f2bf(sB[r0 + 1]));
            }
            // ================= PV: O^T += V^T · P^T (V hi/lo) =================
            // Lane needs kv run [ks*16+hb*8, +8): keep my W[s'=sa+hb], SEND my
            // W[sa+1-hb] (partner's slot) through shfl_xor(32).
#pragma unroll
            for (int ks = 0; ks < 4; ++ks) {
                const int Mt = ks >> 1;
                const int sa = (ks & 1) * 2;
                const unsigned int keep0 = hb ? W[Mt * 8 + (sa + 1) * 2 + 0]
                                              : W[Mt * 8 + sa * 2 + 0];
                const unsigned int keep1 = hb ? W[Mt * 8 + (sa + 1) * 2 + 1]
                                              : W[Mt * 8 + sa * 2 + 1];
                const unsigned int send0 = hb ? W[Mt * 8 + sa * 2 + 0]
                                              : W[Mt * 8 + (sa + 1) * 2 + 0];
                const unsigned int send1 = hb ? W[Mt * 8 + sa * 2 + 1]
                                              : W[Mt * 8 + (sa + 1) * 2 + 1];
                const unsigned int swp0 = (unsigned int)__shfl_xor((int)send0, 32, 64);
                const unsigned int swp1 = (unsigned int)__shfl_xor((int)send1, 32, 64);
                union { unsigned int u[4]; s8x v; } pf;
                pf.u[0] = hb ? swp0 : keep0;
                pf.u[1] = hb ? swp1 : keep1;
                pf.u[2] = hb ? keep0 : swp0;
                pf.u[3] = hb ? keep1 : swp1;
                const int wvv = ((ks * 8 + hb * 4) ^ (gv << 2)) * 4;
                const s8x vAh = *(const s8x*)(ldsb + bb + 16384 + c * 128 + wvv);
                const s8x vAl = *(const s8x*)(ldsb + bb + 24576 + c * 128 + wvv);
                const s8x vBh = *(const s8x*)(ldsb + bb + 16384 + (32 + c) * 128 + wvv);
                const s8x vBl = *(const s8x*)(ldsb + bb + 24576 + (32 + c) * 128 + wvv);
                oA = __builtin_amdgcn_mfma_f32_32x32x16_bf16(vAh, pf.v, oA, 0, 0, 0);
                oA = __builtin_amdgcn_mfma_f32_32x32x16_bf16(vAl, pf.v, oA, 0, 0, 0);
                oB = __builtin_amdgcn_mfma_f32_32x32x16_bf16(vBh, pf.v, oB, 0, 0, 0);
                oB = __builtin_amdgcn_mfma_f32_32x32x16_bf16(vBl, pf.v, oB, 0, 0, 0);
            }
        }
        __syncthreads();   // drains vmcnt (next tile landed) + protects buffers
    }
    // ================= epilogue: O[q][d] = o/l =================
    const float inv = 1.0f / l;
    float* Orow = O + bh_off + (size_t)qg * 1024;
#pragma unroll
    for (int i2 = 0; i2 < 16; ++i2) {
        const int d = (i2 & 3) + 8 * (i2 >> 2) + 4 * hb;
        Orow[d]      = oA[i2] * inv;
        Orow[32 + d] = oB[i2] * inv;
    }
}

// ===================== fallback: R6 monolithic kernel (passed, 226us) =====================
__global__ __launch_bounds__(256, 1)
void attn_mfma_fb(const float* __restrict__ Q, const float* __restrict__ K,
                  const float* __restrict__ V, const float* __restrict__ scale_p,
                  float* __restrict__ O) {
    __shared__ unsigned int lds[8192];
    const int tid  = threadIdx.x;
    const int lane = tid & 63;
    const int wv   = tid >> 6;
    const int c    = lane & 31;
    const int hb   = lane >> 5;
    const int bh   = blockIdx.x & 31;
    const int jj   = blockIdx.x >> 5;
    const int b    = bh >> 4;
    const int h    = bh & 15;
    const float scale = *scale_p;
    const int gk = c & 7;
    const int gv = (((c >> 2) & 3) << 1) | (c & 1);
    const size_t bh_off = ((size_t)b * L_ * H_ + h) * E_;
    const char* ldsb = (const char*)lds;

    for (int ci = 0; ci < 2; ++ci) {
        const int qt  = ci ? (15 - jj) : jj;
        const int q0w = qt * 128 + wv * 32;
        const int qg  = q0w + c;
        const float* Qrow = Q + bh_off + (size_t)qg * 1024;
        s8x qh[4], ql[4];
#pragma unroll
        for (int ks = 0; ks < 4; ++ks) {
            const float* qp = Qrow + ks * 16 + hb * 8;
            float4 f0 = *(const float4*)(qp);
            float4 f1 = *(const float4*)(qp + 4);
            float qv[8] = {f0.x, f0.y, f0.z, f0.w, f1.x, f1.y, f1.z, f1.w};
            union { unsigned short u[8]; s8x v; } th, tl;
#pragma unroll
            for (int e = 0; e < 8; ++e) {
                const float fs = qv[e] * scale;
                const unsigned short hh = f2bf(fs);
                th.u[e] = hh;
                tl.u[e] = f2bf(fs - bf2f(hh));
            }
            qh[ks] = th.v; ql[ks] = tl.v;
        }
        f16x sA, sB, oA, oB;
#pragma unroll
        for (int i2 = 0; i2 < 16; ++i2) { oA[i2] = 0.f; oB[i2] = 0.f; }
        float m = -1e30f, l = 0.f;
        const int nt = 2 * qt + 2;
        for (int t = 0; t < nt; ++t) {
            const int j0 = t * 64;
            {
                const float* Kt = K + bh_off + (size_t)j0 * 1024;
                const float* Vt = V + bh_off + (size_t)j0 * 1024;
#pragma unroll
                for (int kk = 0; kk < 4; ++kk) {
                    const int kv = kk * 16 + (tid >> 4);
                    const int e4 = tid & 15;
                    const float4 v = *(const float4*)(Kt + (size_t)kv * 1024 + e4 * 4);
                    const unsigned short hx = f2bf(v.x), hy = f2bf(v.y),
                                         hz = f2bf(v.z), hw = f2bf(v.w);
                    const unsigned short lx = f2bf(v.x - bf2f(hx)), ly = f2bf(v.y - bf2f(hy)),
                                         lz = f2bf(v.z - bf2f(hz)), lw = f2bf(v.w - bf2f(hw));
                    const int w = (e4 * 2) ^ ((kv & 7) << 2);
                    *(uint2*)&lds[kv * 32 + w]        = make_uint2(pk(hx, hy), pk(hz, hw));
                    *(uint2*)&lds[2048 + kv * 32 + w] = make_uint2(pk(lx, ly), pk(lz, lw));
                }
                const int d4 = (tid & 15) * 4;
                const int kb = tid >> 4;
                const float4 f0 = *(const float4*)(Vt + (size_t)(kb * 4 + 0) * 1024 + d4);
                const float4 f1 = *(const float4*)(Vt + (size_t)(kb * 4 + 1) * 1024 + d4);
                const float4 f2 = *(const float4*)(Vt + (size_t)(kb * 4 + 2) * 1024 + d4);
                const float4 f3 = *(const float4*)(Vt + (size_t)(kb * 4 + 3) * 1024 + d4);
#pragma unroll
                for (int qq = 0; qq < 4; ++qq) {
                    const float e0 = ((const float*)&f0)[qq], e1 = ((const float*)&f1)[qq],
                                e2 = ((const float*)&f2)[qq], e3 = ((const float*)&f3)[qq];
                    const unsigned short h0 = f2bf(e0), h1 = f2bf(e1),
                                         h2 = f2bf(e2), h3 = f2bf(e3);
                    const unsigned short l0 = f2bf(e0 - bf2f(h0)), l1 = f2bf(e1 - bf2f(h1)),
                                         l2 = f2bf(e2 - bf2f(h2)), l3 = f2bf(e3 - bf2f(h3));
                    const int d = d4 + qq;
                    const int g = (((d >> 2) & 3) << 1) | (d & 1);
                    const int w = (kb * 2) ^ (g << 2);
                    *(uint2*)&lds[4096 + d * 32 + w] = make_uint2(pk(h0, h1), pk(h2, h3));
                    *(uint2*)&lds[6144 + d * 32 + w] = make_uint2(pk(l0, l1), pk(l2, l3));
                }
            }
            __syncthreads();
            if (j0 <= q0w + 31) {
#pragma unroll
                for (int i2 = 0; i2 < 16; ++i2) { sA[i2] = 0.f; sB[i2] = 0.f; }
#pragma unroll
                for (int ks = 0; ks < 4; ++ks) {
                    const int wq = ((ks * 8 + hb * 4) ^ (gk << 2)) * 4;
                    const s8x kAh = *(const s8x*)(ldsb + c * 128 + wq);
                    const s8x kAl = *(const s8x*)(ldsb + 8192 + c * 128 + wq);
                    const s8x kBh = *(const s8x*)(ldsb + (32 + c) * 128 + wq);
                    const s8x kBl = *(const s8x*)(ldsb + 8192 + (32 + c) * 128 + wq);
                    sA = __builtin_amdgcn_mfma_f32_32x32x16_bf16(kAh, qh[ks], sA, 0, 0, 0);
                    sA = __builtin_amdgcn_mfma_f32_32x32x16_bf16(kAh, ql[ks], sA, 0, 0, 0);
                    sA = __builtin_amdgcn_mfma_f32_32x32x16_bf16(kAl, qh[ks], sA, 0, 0, 0);
                    sB = __builtin_amdgcn_mfma_f32_32x32x16_bf16(kBh, qh[ks], sB, 0, 0, 0);
                    sB = __builtin_amdgcn_mfma_f32_32x32x16_bf16(kBh, ql[ks], sB, 0, 0, 0);
                    sB = __builtin_amdgcn_mfma_f32_32x32x16_bf16(kBl, qh[ks], sB, 0, 0, 0);
                }
                if (j0 + 63 > q0w) {
#pragma unroll
                    for (int i2 = 0; i2 < 16; ++i2) {
                        const int kvl = (i2 & 3) + 8 * (i2 >> 2) + 4 * hb;
                        sA[i2] = (j0 + kvl > qg)      ? -1e30f : sA[i2];
                        sB[i2] = (j0 + 32 + kvl > qg) ? -1e30f : sB[i2];
                    }
                }
                float mt = -1e30f;
#pragma unroll
                for (int i2 = 0; i2 < 16; ++i2) { mt = fmaxf(mt, sA[i2]); mt = fmaxf(mt, sB[i2]); }
                mt = fmaxf(mt, __shfl_xor(mt, 32, 64));
                const float mn = fmaxf(m, mt);
                const float fr = __expf(m - mn);
                m = mn;
                l *= fr;
#pragma unroll
                for (int i2 = 0; i2 < 16; ++i2) { oA[i2] *= fr; oB[i2] *= fr; }
                float lt = 0.f;
#pragma unroll
                for (int i2 = 0; i2 < 16; ++i2) {
                    const float pA = __expf(sA[i2] - m);
                    const float pB = __expf(sB[i2] - m);
                    sA[i2] = pA; sB[i2] = pB;
                    lt += pA + pB;
                }
                lt += __shfl_xor(lt, 32, 64);
                l += lt;
                unsigned int W[16];
#pragma unroll
                for (int ss = 0; ss < 4; ++ss)
#pragma unroll
                for (int hh2 = 0; hh2 < 2; ++hh2) {
                    const int r0 = 4 * ss + 2 * hh2;
                    W[ss * 2 + hh2]     = pk(f2bf(sA[r0]), f2bf(sA[r0 + 1]));
                    W[8 + ss * 2 + hh2] = pk(f2bf(sB[r0]), f2bf(sB[r0 + 1]));
                }
#pragma unroll
                for (int ks = 0; ks < 4; ++ks) {
                    const int Mt = ks >> 1;
                    const int sa = (ks & 1) * 2;
                    const unsigned int keep0 = hb ? W[Mt * 8 + (sa + 1) * 2 + 0]
                                                  : W[Mt * 8 + sa * 2 + 0];
                    const unsigned int keep1 = hb ? W[Mt * 8 + (sa + 1) * 2 + 1]
                                                  : W[Mt * 8 + sa * 2 + 1];
                    const unsigned int send0 = hb ? W[Mt * 8 + sa * 2 + 0]
                                                  : W[Mt * 8 + (sa + 1) * 2 + 0];
                    const unsigned int send1 = hb ? W[Mt * 8 + sa * 2 + 1]
                                                  : W[Mt * 8 + (sa + 1) * 2 + 1];
                    const unsigned int swp0 = (unsigned int)__shfl_xor((int)send0, 32, 64);
                    const unsigned int swp1 = (unsigned int)__shfl_xor((int)send1, 32, 64);
                    union { unsigned int u[4]; s8x v; } pf;
                    pf.u[0] = hb ? swp0 : keep0;
                    pf.u[1] = hb ? swp1 : keep1;
                    pf.u[2] = hb ? keep0 : swp0;
                    pf.u[3] = hb ? keep1 : swp1;
                    const int wvv = ((ks * 8 + hb * 4) ^ (gv << 2)) * 4;
                    const s8x vAh = *(const s8x*)(ldsb + 16384 + c * 128 + wvv);
                    const s8x vAl = *(const s8x*)(ldsb + 24576 + c * 128 + wvv);
                    const s8x vBh = *(const s8x*)(ldsb + 16384 + (32 + c) * 128 + wvv);
                    const s8x vBl = *(const s8x*)(ldsb + 24576 + (32 + c) * 128 + wvv);
                    oA = __builtin_amdgcn_mfma_f32_32x32x16_bf16(vAh, pf.v, oA, 0, 0, 0);
                    oA = __builtin_amdgcn_mfma_f32_32x32x16_bf16(vAl, pf.v, oA, 0, 0, 0);
                    oB = __builtin_amdgcn_mfma_f32_32x32x16_bf16(vBh, pf.v, oB, 0, 0, 0);
                    oB = __builtin_amdgcn_mfma_f32_32x32x16_bf16(vBl, pf.v, oB, 0, 0, 0);
                }
            }
            __syncthreads();
        }
        const float inv = 1.0f / l;
        float* Orow = O + bh_off + (size_t)qg * 1024;
#pragma unroll
        for (int i2 = 0; i2 < 16; ++i2) {
            const int d = (i2 & 3) + 8 * (i2 >> 2) + 4 * hb;
            Orow[d]      = oA[i2] * inv;
            Orow[32 + d] = oB[i2] * inv;
        }
    }
}

extern "C" void kernel_launch(void* const* d_in, const int* in_sizes, int n_in,
                              void* d_out, int out_size, void* d_ws, size_t ws_size,
                              hipStream_t stream) {
    const float* Q = (const float*)d_in[0];
    const float* K = (const float*)d_in[1];
    const float* V = (const float*)d_in[2];
    const float* scale = (const float*)d_in[3];
    float* O = (float*)d_out;

    const size_t need = (size_t)32 * 32 * 32768;   // 32 bh x 32 tiles x 32KB = 33.5MB
    if (ws_size >= need) {
        unsigned int* WS = (unsigned int*)d_ws;
        pack_kv<<<dim3(1024), 256, 0, stream>>>(K, V, WS);
        attn_mfma_ws<<<dim3(512), 256, 0, stream>>>(Q, WS, scale, O);
    } else {
        attn_mfma_fb<<<dim3(256), 256, 0, stream>>>(Q, K, V, scale, O);
    }
}